// Round 1
// 477.447 us; speedup vs baseline: 1.1136x; 1.1136x over previous
//
#include <hip/hip_runtime.h>
#include <math.h>

#define PI2 6.2831853071795864769f

// Problem constants: B=16, C_in=C_out=64, H=W=256, MH=8, MW=12
// NIMG = B*C = 1024 images each direction.

// ---------------------------------------------------------------------------
// K1: forward H-DFT then W-DFT for one input image per block (unchanged math).
// Output layout changed to Xm[b][pos][i] (float2) so K2's mode-mix stage can
// load its b-slice fully coalesced.
// ---------------------------------------------------------------------------
__global__ __launch_bounds__(256) void k1_fwd(const float* __restrict__ x,
                                              float* __restrict__ Xm) {
  __shared__ float tw[128][16];   // [h][ky*2 + {cos, -sin}]  8 KB
  __shared__ float lds[2][4096];  // [buf][(ky*256+w)*2 + {re,im}]  32 KB
  const int img  = blockIdx.x;
  const int wv   = threadIdx.x >> 6;
  const int lane = threadIdx.x & 63;

  // Fill twiddle table: 128 h x 8 ky, 2 threads per h.
  {
    int h = threadIdx.x >> 1;
    int kyb = (threadIdx.x & 1) * 4;
#pragma unroll
    for (int j = 0; j < 4; ++j) {
      int ky = kyb + j;
      float th = PI2 * (float)((ky * h) & 255) * (1.0f / 256.0f);
      float s_, c_;
      __sincosf(th, &s_, &c_);
      tw[h][ky * 2] = c_;
      tw[h][ky * 2 + 1] = -s_;
    }
  }
  __syncthreads();

  float aR[8][4], aI[8][4];
#pragma unroll
  for (int ky = 0; ky < 8; ++ky)
#pragma unroll
    for (int j = 0; j < 4; ++j) { aR[ky][j] = 0.0f; aI[ky][j] = 0.0f; }

  const float* xa = x + (size_t)img * 65536 + (size_t)(wv * 32) * 256 + lane * 4;
  const float* xb = xa + 128 * 256;
  for (int it = 0; it < 32; ++it) {
    const int h = wv * 32 + it;
    float4 va = *(const float4*)xa;
    float4 vb = *(const float4*)xb;
    xa += 256; xb += 256;
    float p0 = va.x + vb.x, p1 = va.y + vb.y, p2 = va.z + vb.z, p3 = va.w + vb.w;
    float m0 = va.x - vb.x, m1 = va.y - vb.y, m2 = va.z - vb.z, m3 = va.w - vb.w;
#pragma unroll
    for (int ky = 0; ky < 8; ++ky) {
      float c  = tw[h][ky * 2];
      float ns = tw[h][ky * 2 + 1];  // == -sin
      float u0, u1, u2, u3;
      if (ky & 1) { u0 = m0; u1 = m1; u2 = m2; u3 = m3; }
      else        { u0 = p0; u1 = p1; u2 = p2; u3 = p3; }
      aR[ky][0] = fmaf(u0, c, aR[ky][0]);  aI[ky][0] = fmaf(u0, ns, aI[ky][0]);
      aR[ky][1] = fmaf(u1, c, aR[ky][1]);  aI[ky][1] = fmaf(u1, ns, aI[ky][1]);
      aR[ky][2] = fmaf(u2, c, aR[ky][2]);  aI[ky][2] = fmaf(u2, ns, aI[ky][2]);
      aR[ky][3] = fmaf(u3, c, aR[ky][3]);  aI[ky][3] = fmaf(u3, ns, aI[ky][3]);
    }
  }

  // Combine 4 wave-partials: waves 0,1 store; waves 2,3 add; then buf0+=buf1.
  if (wv < 2) {
#pragma unroll
    for (int ky = 0; ky < 8; ++ky)
#pragma unroll
      for (int j = 0; j < 4; ++j) {
        int p = (ky * 256 + lane * 4 + j) * 2;
        lds[wv][p] = aR[ky][j];
        lds[wv][p + 1] = aI[ky][j];
      }
  }
  __syncthreads();
  if (wv >= 2) {
#pragma unroll
    for (int ky = 0; ky < 8; ++ky)
#pragma unroll
      for (int j = 0; j < 4; ++j) {
        int p = (ky * 256 + lane * 4 + j) * 2;
        lds[wv - 2][p] += aR[ky][j];
        lds[wv - 2][p + 1] += aI[ky][j];
      }
  }
  __syncthreads();
  for (int f = threadIdx.x; f < 4096; f += 256) lds[0][f] += lds[1][f];
  __syncthreads();

  // w-DFT: 96 threads, one (ky,kx) each; serial over 256 w from LDS.
  if (threadIdx.x < 96) {
    int ky = threadIdx.x / 12, kx = threadIdx.x % 12;
    float Cw, Sw;
    __sincosf(PI2 * (float)kx * (1.0f / 256.0f), &Sw, &Cw);
    float c = 1.0f, s = 0.0f, Xr = 0.0f, Xi = 0.0f;
    const float* base = &lds[0][ky * 512];
    for (int w = 0; w < 256; ++w) {
      float Sre = base[w * 2], Sim = base[w * 2 + 1];
      Xr += Sre * c + Sim * s;
      Xi += Sim * c - Sre * s;
      float nc = fmaf(c, Cw, -s * Sw);
      s = fmaf(s, Cw, c * Sw);
      c = nc;
    }
    float2 v = { Xr * (1.0f / 256.0f), Xi * (1.0f / 256.0f) };
    // New layout: Xm2[b][pos][i]  (pos = this thread, img = b*64 + i)
    const int bb = img >> 6, ii = img & 63;
    ((float2*)Xm)[(size_t)(bb * 96 + threadIdx.x) * 64 + ii] = v;
  }
}

// ---------------------------------------------------------------------------
// K2: fused mode-mix + inverse H + inverse W.  One block per output image
// img2 = b*64 + o.
//
// Stage 1 (k3): Fm[pos] = sum_i Xm[b][pos][i] * W[i][o][pos], i chunked in 2
//   halves staged through LDS (coalesced global loads). 96 threads compute.
// Stage 2 (k4a): thread h computes U[h][24] = alpha/256 * inv-H(Fm) and
//   writes the row to LDS (24 KB).  U never touches global memory.
// Stage 3 (k4b): wave wv owns h-strip [64wv,64wv+64); lane = w2 in [0,64).
//   Per h, ONE 96 B broadcast row read yields FOUR pixels per lane via the
//   quarter-period symmetry w2, w2+64, w2+128, w2+192:
//     contrib(kx, w2+64q) rotates (cos,sin) by q*pi/2*kx -> split kx by
//     kx&3 into class sums A0..A3 (and B1,B3 for odd classes):
//       out(w2)     = A0+A1+A2+A3
//       out(w2+64)  = A0-B1-A2+B3
//       out(w2+128) = A0-A1+A2-A3
//       out(w2+192) = A0+B1-A2-B3
//   36 FMA / 4 px, broadcast RF-fill cut 16x vs thread-per-w, stores stay
//   fully coalesced (4 x 256 B per wave per row).
// ---------------------------------------------------------------------------
__global__ __launch_bounds__(256) void k2_fused(const float* __restrict__ Xm,
                                                const float* __restrict__ wt,
                                                float* __restrict__ outp) {
  __shared__ float sh[6528];  // union: xb[96][68] (26.1 KB) / U[256][24] (24 KB)
  __shared__ float Fs[192];
  const int img2 = blockIdx.x;
  const int b = img2 >> 6, o = img2 & 63;
  const int tid = threadIdx.x;

  // ---- stage 1: mode mixing ----
  float fr = 0.0f, fi = 0.0f;
#pragma unroll
  for (int c = 0; c < 2; ++c) {
    // Coalesced load of i-chunk: floats [c*64, c*64+64) of each 128-float
    // pos-row of this b-slice.  96*64 floats as float4.
    for (int idx = tid; idx < 1536; idx += 256) {
      int p = idx >> 4, j4 = idx & 15;
      float4 v = ((const float4*)(Xm + (size_t)(b * 96 + p) * 128 + c * 64))[j4];
      ((float4*)(sh + p * 68))[j4] = v;
    }
    __syncthreads();
    if (tid < 96) {
      const int pos = tid;
      // wt float idx = ((i*64+o)*96+pos)*2, i = 32c+jj
      const float* wrow = wt + ((size_t)(c * 2048 + o) * 96 + pos) * 2;
#pragma unroll 8
      for (int jj = 0; jj < 32; ++jj) {
        float xr = sh[pos * 68 + 2 * jj];
        float xi = sh[pos * 68 + 2 * jj + 1];
        float wr = wrow[(size_t)jj * 12288];
        float wi = wrow[(size_t)jj * 12288 + 1];
        fr += xr * wr - xi * wi;
        fi += xr * wi + xi * wr;
      }
    }
    __syncthreads();
  }
  if (tid < 96) { Fs[tid * 2] = fr; Fs[tid * 2 + 1] = fi; }
  __syncthreads();

  // ---- stage 2: inverse H, alpha/256 folded; U rows into LDS ----
  {
    const int h = tid;
    float cc[8], ss[8];
#pragma unroll
    for (int ky = 0; ky < 8; ++ky) {
      float th = PI2 * (float)((ky * h) & 255) * (1.0f / 256.0f);
      __sincosf(th, &ss[ky], &cc[ky]);
    }
    float4 ov4[6];
    float* ov = (float*)ov4;
#pragma unroll
    for (int kx = 0; kx < 12; ++kx) {
      float Ur = 0.0f, Ui = 0.0f;
#pragma unroll
      for (int ky = 0; ky < 8; ++ky) {
        float Fr = Fs[(ky * 12 + kx) * 2], Fi = Fs[(ky * 12 + kx) * 2 + 1];
        Ur += Fr * cc[ky] - Fi * ss[ky];
        Ui += Fr * ss[ky] + Fi * cc[ky];
      }
      float a = (kx == 0 ? 1.0f : 2.0f) * (1.0f / 256.0f);
      ov[kx * 2] = Ur * a;
      ov[kx * 2 + 1] = Ui * a;
    }
    float4* dst = (float4*)(sh + h * 24);   // h*96 B, 16 B aligned
#pragma unroll
    for (int k = 0; k < 6; ++k) dst[k] = ov4[k];
  }
  __syncthreads();

  // ---- stage 3: inverse W with quarter-period symmetry ----
  {
    const int wv = tid >> 6, lane = tid & 63;  // lane = w2
    float cx[12], sx[12];
#pragma unroll
    for (int kx = 0; kx < 12; ++kx) {
      float th = PI2 * (float)((kx * lane) & 255) * (1.0f / 256.0f);
      __sincosf(th, &sx[kx], &cx[kx]);
    }
    float* ob = outp + (size_t)img2 * 65536 + lane;
    for (int l0 = 0; l0 < 64; ++l0) {
      const int h = wv * 64 + l0;
      const float4* ur = (const float4*)(sh + h * 24);  // uniform broadcast
      float u[24];
#pragma unroll
      for (int k = 0; k < 6; ++k) {
        float4 q = ur[k];
        u[4 * k] = q.x; u[4 * k + 1] = q.y; u[4 * k + 2] = q.z; u[4 * k + 3] = q.w;
      }
      float A[4] = {0.0f, 0.0f, 0.0f, 0.0f};
      float B1 = 0.0f, B3 = 0.0f;
#pragma unroll
      for (int kx = 0; kx < 12; ++kx) {
        const int cls = kx & 3;
        A[cls] = fmaf(u[2 * kx], cx[kx], A[cls]);
        A[cls] = fmaf(-u[2 * kx + 1], sx[kx], A[cls]);
        if (cls == 1) {
          B1 = fmaf(u[2 * kx], sx[kx], B1);
          B1 = fmaf(u[2 * kx + 1], cx[kx], B1);
        }
        if (cls == 3) {
          B3 = fmaf(u[2 * kx], sx[kx], B3);
          B3 = fmaf(u[2 * kx + 1], cx[kx], B3);
        }
      }
      float t0 = A[0] + A[2], t1 = A[1] + A[3];
      float t2 = A[0] - A[2], t3 = B3 - B1;
      float* row = ob + h * 256;
      row[0]   = t0 + t1;
      row[64]  = t2 + t3;
      row[128] = t0 - t1;
      row[192] = t2 - t3;
    }
  }
}

extern "C" void kernel_launch(void* const* d_in, const int* in_sizes, int n_in,
                              void* d_out, int out_size, void* d_ws, size_t ws_size,
                              hipStream_t stream) {
  const float* x  = (const float*)d_in[0];   // (16,64,256,256)
  const float* wt = (const float*)d_in[1];   // (64,64,8,12,2)
  float* outp = (float*)d_out;               // (16,64,256,256)

  float* Xm = (float*)d_ws;  // [16][96][64][2] = 196608 floats (768 KB)

  k1_fwd  <<<1024, 256, 0, stream>>>(x, Xm);
  k2_fused<<<1024, 256, 0, stream>>>(Xm, wt, outp);
}

// Round 2
// 471.073 us; speedup vs baseline: 1.1286x; 1.0135x over previous
//
#include <hip/hip_runtime.h>
#include <math.h>

#define PI2 6.2831853071795864769f

// Problem constants: B=16, C_in=C_out=64, H=W=256, MH=8, MW=12
// NIMG = B*C = 1024 images each direction.

// ---------------------------------------------------------------------------
// K1: forward H-DFT then W-DFT for one input image per block.
// Changes vs prev round:
//  - S-matrix LDS layout transposed to p = w*17 + ky*2 (+reim). Stride 17
//    floats: tail readers (distinct ky) hit distinct banks (<=2-way = free),
//    combine writers cycle 8 banks (was 16-way on bank 0).
//  - Twiddle table shrunk 8KB -> 2KB: one 256-entry (cos,sin) float2 table,
//    broadcast b64 reads, per-ky index walked incrementally. Keeps LDS at
//    36.7 KB -> 4 blocks/CU.
//  - w-DFT tail split 2x: 192 threads = (pos, half), half*128 w each; start
//    twiddle at w=128 is (-1)^kx exactly. Partials combined via tiny LDS
//    scratch. Final pre-combine 4096-pass + 1 barrier removed (tail reads
//    buf0+buf1 inline).
// ---------------------------------------------------------------------------
__global__ __launch_bounds__(256, 4) void k1_fwd(const float* __restrict__ x,
                                                 float* __restrict__ Xm) {
  __shared__ float2 ctab[256];     // (cos, sin)(2pi t/256)   2 KB
  __shared__ float lds[2][4352];   // [buf][w*17 + ky*2 + reim]  34.8 KB
  __shared__ float scr[192];       // tail partial (Xr,Xi) for half=1  768 B
  const int img  = blockIdx.x;
  const int wv   = threadIdx.x >> 6;
  const int lane = threadIdx.x & 63;

  {
    float s_, c_;
    __sincosf(PI2 * (float)threadIdx.x * (1.0f / 256.0f), &s_, &c_);
    ctab[threadIdx.x] = make_float2(c_, s_);
  }
  __syncthreads();

  float aR[8][4], aI[8][4];
#pragma unroll
  for (int ky = 0; ky < 8; ++ky)
#pragma unroll
    for (int j = 0; j < 4; ++j) { aR[ky][j] = 0.0f; aI[ky][j] = 0.0f; }

  const float* xa = x + (size_t)img * 65536 + (size_t)(wv * 32) * 256 + lane * 4;
  const float* xb = xa + 128 * 256;
  int idx[8];
#pragma unroll
  for (int ky = 0; ky < 8; ++ky) idx[ky] = (ky * (wv * 32)) & 255;

  for (int it = 0; it < 32; ++it) {
    float4 va = *(const float4*)xa;
    float4 vb = *(const float4*)xb;
    xa += 256; xb += 256;
    float p0 = va.x + vb.x, p1 = va.y + vb.y, p2 = va.z + vb.z, p3 = va.w + vb.w;
    float m0 = va.x - vb.x, m1 = va.y - vb.y, m2 = va.z - vb.z, m3 = va.w - vb.w;
#pragma unroll
    for (int ky = 0; ky < 8; ++ky) {
      float2 cs = ctab[idx[ky]];       // broadcast b64
      float c  = cs.x;
      float ns = -cs.y;                // forward DFT uses (cos, -sin)
      idx[ky] = (idx[ky] + ky) & 255;
      float u0, u1, u2, u3;
      if (ky & 1) { u0 = m0; u1 = m1; u2 = m2; u3 = m3; }
      else        { u0 = p0; u1 = p1; u2 = p2; u3 = p3; }
      aR[ky][0] = fmaf(u0, c, aR[ky][0]);  aI[ky][0] = fmaf(u0, ns, aI[ky][0]);
      aR[ky][1] = fmaf(u1, c, aR[ky][1]);  aI[ky][1] = fmaf(u1, ns, aI[ky][1]);
      aR[ky][2] = fmaf(u2, c, aR[ky][2]);  aI[ky][2] = fmaf(u2, ns, aI[ky][2]);
      aR[ky][3] = fmaf(u3, c, aR[ky][3]);  aI[ky][3] = fmaf(u3, ns, aI[ky][3]);
    }
  }

  // Combine 4 wave-partials: waves 0,1 store to buf0,buf1; waves 2,3 add.
  // Layout p(w, ky) = w*17 + ky*2 (+reim).
  if (wv < 2) {
#pragma unroll
    for (int ky = 0; ky < 8; ++ky)
#pragma unroll
      for (int j = 0; j < 4; ++j) {
        int p = (lane * 4 + j) * 17 + ky * 2;
        lds[wv][p]     = aR[ky][j];
        lds[wv][p + 1] = aI[ky][j];
      }
  }
  __syncthreads();
  if (wv >= 2) {
#pragma unroll
    for (int ky = 0; ky < 8; ++ky)
#pragma unroll
      for (int j = 0; j < 4; ++j) {
        int p = (lane * 4 + j) * 17 + ky * 2;
        lds[wv - 2][p]     += aR[ky][j];
        lds[wv - 2][p + 1] += aI[ky][j];
      }
  }
  __syncthreads();

  // w-DFT: 192 threads = (pos, half); half covers w in [128*half, 128*half+128).
  // buf0+buf1 summed inline (no pre-combine pass).
  float Xr = 0.0f, Xi = 0.0f;
  if (threadIdx.x < 192) {
    const int pos  = threadIdx.x % 96;
    const int half = threadIdx.x / 96;
    const int ky = pos / 12, kx = pos % 12;
    float Cw, Sw;
    __sincosf(PI2 * (float)kx * (1.0f / 256.0f), &Sw, &Cw);
    float c = ((kx & 1) && half) ? -1.0f : 1.0f;  // cos(pi*kx) at w0=128
    float s = 0.0f;
    const float* b0 = &lds[0][(half * 128) * 17 + ky * 2];
    const float* b1 = &lds[1][(half * 128) * 17 + ky * 2];
    for (int w = 0; w < 128; ++w) {
      float Sre = b0[w * 17]     + b1[w * 17];
      float Sim = b0[w * 17 + 1] + b1[w * 17 + 1];
      Xr += Sre * c + Sim * s;
      Xi += Sim * c - Sre * s;
      float nc = fmaf(c, Cw, -s * Sw);
      s = fmaf(s, Cw, c * Sw);
      c = nc;
    }
    if (threadIdx.x >= 96) {
      scr[(threadIdx.x - 96) * 2]     = Xr;
      scr[(threadIdx.x - 96) * 2 + 1] = Xi;
    }
  }
  __syncthreads();
  if (threadIdx.x < 96) {
    float xr = (Xr + scr[threadIdx.x * 2])     * (1.0f / 256.0f);
    float xi = (Xi + scr[threadIdx.x * 2 + 1]) * (1.0f / 256.0f);
    // Layout: Xm[b][pos][i]  (pos = this thread, img = b*64 + i)
    const int bb = img >> 6, ii = img & 63;
    float2 v = { xr, xi };
    ((float2*)Xm)[(size_t)(bb * 96 + threadIdx.x) * 64 + ii] = v;
  }
}

// ---------------------------------------------------------------------------
// K2: fused mode-mix + inverse H + inverse W.  One block per output image
// img2 = b*64 + o.
//
// Stage 1 (mix): Fm[pos] = sum_i Xm[b][pos][i] * W[i][o][pos], i chunked in 2
//   LDS-staged halves; NOW mixed by 192 threads = (pos, ihalf) with 16 i each,
//   partials combined through Fs (was 96 threads x 32 i serial).
// Stage 2: thread h computes U[h][24] = alpha/256 * inv-H(Fm) -> LDS (24 KB).
// Stage 3: wave wv owns h-strip; lane = w2; quarter-period symmetry gives
//   4 pixels per lane per 96 B broadcast row read (unchanged).
// ---------------------------------------------------------------------------
__global__ __launch_bounds__(256) void k2_fused(const float* __restrict__ Xm,
                                                const float* __restrict__ wt,
                                                float* __restrict__ outp) {
  __shared__ float sh[6528];  // union: xb[96][68] (26.1 KB) / U[256][24] (24 KB)
  __shared__ float Fs[192];
  const int img2 = blockIdx.x;
  const int b = img2 >> 6, o = img2 & 63;
  const int tid = threadIdx.x;

  // ---- stage 1: mode mixing (2-way i-split over 192 threads) ----
  float fr = 0.0f, fi = 0.0f;
  const int mpos = tid % 96;
  const int mh2  = tid / 96;   // 0 or 1 for tid<192
#pragma unroll
  for (int c = 0; c < 2; ++c) {
    // Coalesced stage of i-chunk: floats [c*64, c*64+64) of each 128-float
    // pos-row of this b-slice. 96*64 floats as float4.
    for (int idx = tid; idx < 1536; idx += 256) {
      int p = idx >> 4, j4 = idx & 15;
      float4 v = ((const float4*)(Xm + (size_t)(b * 96 + p) * 128 + c * 64))[j4];
      ((float4*)(sh + p * 68))[j4] = v;
    }
    __syncthreads();
    if (tid < 192) {
      // i = c*32 + mh2*16 + jj, jj in [0,16)
      const float* wrow =
          wt + (((size_t)(c * 32 + mh2 * 16) * 64 + o) * 96 + mpos) * 2;
      const float* xrow = sh + mpos * 68 + mh2 * 32;
#pragma unroll
      for (int jj = 0; jj < 16; ++jj) {
        float xr = xrow[2 * jj];
        float xi = xrow[2 * jj + 1];
        float wr = wrow[(size_t)jj * 12288];
        float wi = wrow[(size_t)jj * 12288 + 1];
        fr += xr * wr - xi * wi;
        fi += xr * wi + xi * wr;
      }
    }
    __syncthreads();
  }
  if (tid >= 96 && tid < 192) {
    Fs[(tid - 96) * 2]     = fr;
    Fs[(tid - 96) * 2 + 1] = fi;
  }
  __syncthreads();
  if (tid < 96) {
    Fs[tid * 2]     += fr;
    Fs[tid * 2 + 1] += fi;
  }
  __syncthreads();

  // ---- stage 2: inverse H, alpha/256 folded; U rows into LDS ----
  {
    const int h = tid;
    float cc[8], ss[8];
#pragma unroll
    for (int ky = 0; ky < 8; ++ky) {
      float th = PI2 * (float)((ky * h) & 255) * (1.0f / 256.0f);
      __sincosf(th, &ss[ky], &cc[ky]);
    }
    float4 ov4[6];
    float* ov = (float*)ov4;
#pragma unroll
    for (int kx = 0; kx < 12; ++kx) {
      float Ur = 0.0f, Ui = 0.0f;
#pragma unroll
      for (int ky = 0; ky < 8; ++ky) {
        float Fr = Fs[(ky * 12 + kx) * 2], Fi = Fs[(ky * 12 + kx) * 2 + 1];
        Ur += Fr * cc[ky] - Fi * ss[ky];
        Ui += Fr * ss[ky] + Fi * cc[ky];
      }
      float a = (kx == 0 ? 1.0f : 2.0f) * (1.0f / 256.0f);
      ov[kx * 2] = Ur * a;
      ov[kx * 2 + 1] = Ui * a;
    }
    float4* dst = (float4*)(sh + h * 24);   // h*96 B, 16 B aligned
#pragma unroll
    for (int k = 0; k < 6; ++k) dst[k] = ov4[k];
  }
  __syncthreads();

  // ---- stage 3: inverse W with quarter-period symmetry ----
  {
    const int wv = tid >> 6, lane = tid & 63;  // lane = w2
    float cx[12], sx[12];
#pragma unroll
    for (int kx = 0; kx < 12; ++kx) {
      float th = PI2 * (float)((kx * lane) & 255) * (1.0f / 256.0f);
      __sincosf(th, &sx[kx], &cx[kx]);
    }
    float* ob = outp + (size_t)img2 * 65536 + lane;
    for (int l0 = 0; l0 < 64; ++l0) {
      const int h = wv * 64 + l0;
      const float4* ur = (const float4*)(sh + h * 24);  // uniform broadcast
      float u[24];
#pragma unroll
      for (int k = 0; k < 6; ++k) {
        float4 q = ur[k];
        u[4 * k] = q.x; u[4 * k + 1] = q.y; u[4 * k + 2] = q.z; u[4 * k + 3] = q.w;
      }
      float A[4] = {0.0f, 0.0f, 0.0f, 0.0f};
      float B1 = 0.0f, B3 = 0.0f;
#pragma unroll
      for (int kx = 0; kx < 12; ++kx) {
        const int cls = kx & 3;
        A[cls] = fmaf(u[2 * kx], cx[kx], A[cls]);
        A[cls] = fmaf(-u[2 * kx + 1], sx[kx], A[cls]);
        if (cls == 1) {
          B1 = fmaf(u[2 * kx], sx[kx], B1);
          B1 = fmaf(u[2 * kx + 1], cx[kx], B1);
        }
        if (cls == 3) {
          B3 = fmaf(u[2 * kx], sx[kx], B3);
          B3 = fmaf(u[2 * kx + 1], cx[kx], B3);
        }
      }
      float t0 = A[0] + A[2], t1 = A[1] + A[3];
      float t2 = A[0] - A[2], t3 = B3 - B1;
      float* row = ob + h * 256;
      row[0]   = t0 + t1;
      row[64]  = t2 + t3;
      row[128] = t0 - t1;
      row[192] = t2 - t3;
    }
  }
}

extern "C" void kernel_launch(void* const* d_in, const int* in_sizes, int n_in,
                              void* d_out, int out_size, void* d_ws, size_t ws_size,
                              hipStream_t stream) {
  const float* x  = (const float*)d_in[0];   // (16,64,256,256)
  const float* wt = (const float*)d_in[1];   // (64,64,8,12,2)
  float* outp = (float*)d_out;               // (16,64,256,256)

  float* Xm = (float*)d_ws;  // [16][96][64][2] = 196608 floats (768 KB)

  k1_fwd  <<<1024, 256, 0, stream>>>(x, Xm);
  k2_fused<<<1024, 256, 0, stream>>>(Xm, wt, outp);
}